// Round 3
// baseline (5708.723 us; speedup 1.0000x reference)
//
#include <hip/hip_runtime.h>
#include <stdint.h>

#define T_LEN 2048
#define L     1024
#define KBLK  64            // compute blocks (block KBLK is the gold block)
#define CPB   16            // columns per block; 4 per wave
#define TPB   256
#define SPIN_MAX (1 << 17)

#define SCOPE_AGENT __HIP_MEMORY_SCOPE_AGENT

__device__ __forceinline__ uint64_t pack_su(int tag, float v) {
    return ((uint64_t)(uint32_t)tag << 32) | (uint64_t)__float_as_uint(v);
}

__global__ __launch_bounds__(TPB, 1)
void crf_forward(const float* __restrict__ feats,
                 const float* __restrict__ transfer,
                 const int* __restrict__ target,
                 float* __restrict__ out,
                 uint64_t* __restrict__ ws64)
{
    __shared__ float red[8];                        // gold block + epilogue only

    uint64_t* buf0 = ws64;                          // tagged score buffers (double-buffered)
    uint64_t* buf1 = ws64 + L;
    uint64_t* goldslot = ws64 + 2 * L;

    const int b   = blockIdx.x;
    const int tid = threadIdx.x;

    // ---------------- gold-score block (independent of the chain) ----------------
    if (b == KBLK) {
        float s = 0.f;
        for (int t = tid; t < T_LEN; t += TPB)
            s += feats[t * L + target[t]];
        for (int t = tid; t < T_LEN - 1; t += TPB)
            s += transfer[target[t] * L + target[t + 1]];
        #pragma unroll
        for (int m = 32; m; m >>= 1) s += __shfl_xor(s, m, 64);
        if ((tid & 63) == 0) red[tid >> 6] = s;
        __syncthreads();
        if (tid == 0) {
            float g = red[0] + red[1] + red[2] + red[3];
            __hip_atomic_store(goldslot, pack_su(1, g), __ATOMIC_RELAXED, SCOPE_AGENT);
        }
        return;
    }

    const int lane = tid & 63;
    const int wv   = tid >> 6;                      // wave 0..3
    const int gcb  = b * CPB + 4 * wv;              // this wave's first global column
    // lane -> column-within-wave mapping fixed by the split-reduction below:
    const int cl   = 2 * (lane & 1) + ((lane >> 1) & 1);   // 0..3, bijective on lanes 0..3

    // ---------------- stage E = exp(transfer) into REGISTERS ----------------
    // lane handles rows i = lane + 64k (k=0..15), columns gcb..gcb+3. 64 fp32 VGPRs.
    float E[16][4];
    #pragma unroll
    for (int k = 0; k < 16; ++k) {
        const float4 r = *(const float4*)(transfer + (lane + 64 * k) * L + gcb);
        E[k][0] = __expf(r.x); E[k][1] = __expf(r.y);
        E[k][2] = __expf(r.z); E[k][3] = __expf(r.w);
    }

    // ---------------- init: step-0 scores = feats[0], tag 0 ----------------
    if (tid < CPB) {
        int j = b * CPB + tid;
        __hip_atomic_store(&buf0[j], pack_su(0, feats[j]), __ATOMIC_RELAXED, SCOPE_AGENT);
    }
    float sloc = feats[gcb];                        // wave-private exp shift (col gcb at t=0)

    // ---------------- sequential chain: NO barriers, NO LDS ----------------
    for (int t = 1; t < T_LEN; ++t) {
        uint64_t* rbuf = (t & 1) ? buf0 : buf1;     // holds step t-1
        uint64_t* wbuf = (t & 1) ? buf1 : buf0;     // will hold step t
        const int expect = t - 1;

        // prefetch this step's emission for my column (overlaps the poll)
        const float fe = feats[t * L + gcb + cl];

        // poll all 1024 slots: lane covers slots lane+64k (coalesced 512B/instr);
        // only stale slots are re-loaded.
        const uint64_t* rp = rbuf + lane;
        uint64_t v[16];
        #pragma unroll
        for (int k = 0; k < 16; ++k)
            v[k] = __hip_atomic_load(rp + 64 * k, __ATOMIC_RELAXED, SCOPE_AGENT);
        int n = 0;
        for (;;) {
            bool ready = true;
            #pragma unroll
            for (int k = 0; k < 16; ++k)
                ready &= ((int)(v[k] >> 32) >= expect);
            if (ready || ++n >= SPIN_MAX) break;
            #pragma unroll
            for (int k = 0; k < 16; ++k)
                if ((int)(v[k] >> 32) < expect)
                    v[k] = __hip_atomic_load(rp + 64 * k, __ATOMIC_RELAXED, SCOPE_AGENT);
        }

        // acc[c] = sum over my 16 rows of exp(prev - sloc) * E[row, c]
        float a0 = 0.f, a1 = 0.f, a2 = 0.f, a3 = 0.f;
        #pragma unroll
        for (int k = 0; k < 16; ++k) {
            const float q = __expf(__uint_as_float((uint32_t)v[k]) - sloc);
            a0 += q * E[k][0]; a1 += q * E[k][1];
            a2 += q * E[k][2]; a3 += q * E[k][3];
        }

        // split-reduction over 64 lanes: 4 accs -> 1 value per lane, col = cl
        {
            const bool hi1 = lane & 1;
            float s0 = hi1 ? a0 : a2;  float r0 = __shfl_xor(s0, 1, 64);
            float s1 = hi1 ? a1 : a3;  float r1 = __shfl_xor(s1, 1, 64);
            a0 = (hi1 ? a2 : a0) + r0;
            a1 = (hi1 ? a3 : a1) + r1;
            const bool hi2 = lane & 2;
            float s2 = hi2 ? a0 : a1;  float r2 = __shfl_xor(s2, 2, 64);
            a0 = (hi2 ? a1 : a0) + r2;
        }
        float s = a0;
        s += __shfl_xor(s, 4, 64);
        s += __shfl_xor(s, 8, 64);
        s += __shfl_xor(s, 16, 64);
        s += __shfl_xor(s, 32, 64);

        const float nv = sloc + __logf(s) + fe;     // new score for column gcb+cl
        if (lane < 4)
            __hip_atomic_store(&wbuf[gcb + cl], pack_su(t, nv), __ATOMIC_RELAXED, SCOPE_AGENT);
        sloc = __shfl(nv, 0, 64);                   // lane 0 holds cl==0 -> next shift
    }

    // ---------------- epilogue: block 0 computes logZ - gold ----------------
    if (b == 0) {
        const uint64_t* fp = buf1 + 4 * tid;        // t=2047 (odd) wrote buf1
        uint64_t v0, v1, v2, v3;
        int n = 0;
        for (;;) {
            v0 = __hip_atomic_load(fp + 0, __ATOMIC_RELAXED, SCOPE_AGENT);
            v1 = __hip_atomic_load(fp + 1, __ATOMIC_RELAXED, SCOPE_AGENT);
            v2 = __hip_atomic_load(fp + 2, __ATOMIC_RELAXED, SCOPE_AGENT);
            v3 = __hip_atomic_load(fp + 3, __ATOMIC_RELAXED, SCOPE_AGENT);
            bool ready = ((int)(v0 >> 32) >= T_LEN - 1) & ((int)(v1 >> 32) >= T_LEN - 1) &
                         ((int)(v2 >> 32) >= T_LEN - 1) & ((int)(v3 >> 32) >= T_LEN - 1);
            if (ready || ++n >= SPIN_MAX) break;
        }
        float sv[4] = { __uint_as_float((uint32_t)v0), __uint_as_float((uint32_t)v1),
                        __uint_as_float((uint32_t)v2), __uint_as_float((uint32_t)v3) };
        float mx = fmaxf(fmaxf(sv[0], sv[1]), fmaxf(sv[2], sv[3]));
        #pragma unroll
        for (int m = 32; m; m >>= 1) mx = fmaxf(mx, __shfl_xor(mx, m, 64));
        if ((tid & 63) == 0) red[tid >> 6] = mx;
        __syncthreads();
        const float M = fmaxf(fmaxf(red[0], red[1]), fmaxf(red[2], red[3]));
        float sm = 0.f;
        #pragma unroll
        for (int k = 0; k < 4; ++k) sm += __expf(sv[k] - M);
        #pragma unroll
        for (int m = 32; m; m >>= 1) sm += __shfl_xor(sm, m, 64);
        if ((tid & 63) == 0) red[4 + (tid >> 6)] = sm;
        __syncthreads();
        if (tid == 0) {
            const float S = red[4] + red[5] + red[6] + red[7];
            const float lse = M + __logf(S);
            uint64_t g = __hip_atomic_load(goldslot, __ATOMIC_RELAXED, SCOPE_AGENT);
            int n2 = 0;
            while ((int)(g >> 32) < 1 && ++n2 < SPIN_MAX)
                g = __hip_atomic_load(goldslot, __ATOMIC_RELAXED, SCOPE_AGENT);
            out[0] = lse - __uint_as_float((uint32_t)g);
        }
    }
}

extern "C" void kernel_launch(void* const* d_in, const int* in_sizes, int n_in,
                              void* d_out, int out_size, void* d_ws, size_t ws_size,
                              hipStream_t stream) {
    const float* feats    = (const float*)d_in[0];
    const float* transfer = (const float*)d_in[1];
    const int*   target   = (const int*)d_in[2];
    float* out = (float*)d_out;
    uint64_t* ws64 = (uint64_t*)d_ws;   // needs (2*L + 1) * 8 = 16392 bytes

    hipLaunchKernelGGL(crf_forward, dim3(KBLK + 1), dim3(TPB), 0, stream,
                       feats, transfer, target, out, ws64);
}

// Round 4
// 4163.478 us; speedup vs baseline: 1.3711x; 1.3711x over previous
//
#include <hip/hip_runtime.h>
#include <stdint.h>

#define T_LEN 2048
#define L     1024
#define KBLK  64            // compute blocks (block KBLK is the gold block)
#define CPB   16            // columns per block; 4 per wave
#define TPB   256
#define SPIN_MAX (1 << 17)

#define SCOPE_AGENT __HIP_MEMORY_SCOPE_AGENT

__device__ __forceinline__ uint64_t pack_su(int tag, float v) {
    return ((uint64_t)(uint32_t)tag << 32) | (uint64_t)__float_as_uint(v);
}

__global__ __launch_bounds__(TPB, 1)
void crf_forward(const float* __restrict__ feats,
                 const float* __restrict__ transfer,
                 const int* __restrict__ target,
                 float* __restrict__ out,
                 uint64_t* __restrict__ ws64)
{
    __shared__ __align__(16) float qbuf[2][L];      // 8 KB: exp(prev - sloc), double-buffered
    __shared__ float red[8];

    uint64_t* buf0 = ws64;                          // tagged score buffers (double-buffered)
    uint64_t* buf1 = ws64 + L;
    uint64_t* goldslot = ws64 + 2 * L;

    const int b   = blockIdx.x;
    const int tid = threadIdx.x;

    // ---------------- gold-score block (independent of the chain) ----------------
    if (b == KBLK) {
        float s = 0.f;
        for (int t = tid; t < T_LEN; t += TPB)
            s += feats[t * L + target[t]];
        for (int t = tid; t < T_LEN - 1; t += TPB)
            s += transfer[target[t] * L + target[t + 1]];
        #pragma unroll
        for (int m = 32; m; m >>= 1) s += __shfl_xor(s, m, 64);
        if ((tid & 63) == 0) red[tid >> 6] = s;
        __syncthreads();
        if (tid == 0) {
            float g = red[0] + red[1] + red[2] + red[3];
            __hip_atomic_store(goldslot, pack_su(1, g), __ATOMIC_RELAXED, SCOPE_AGENT);
        }
        return;
    }

    const int lane = tid & 63;
    const int wv   = tid >> 6;                      // wave 0..3
    const int gcb  = b * CPB + 4 * wv;              // this wave's first global column
    // lane -> column-within-wave mapping fixed by the split-reduction below:
    const int cl   = 2 * (lane & 1) + ((lane >> 1) & 1);   // 0..3, bijective on lanes 0..3
    const int shslot = b * CPB;                     // block-uniform exp-shift source column

    // ---------------- stage E = exp(transfer) into REGISTERS ----------------
    // lane handles rows i = lane + 64k (k=0..15), columns gcb..gcb+3. 64 fp32 VGPRs.
    float E[16][4];
    #pragma unroll
    for (int k = 0; k < 16; ++k) {
        const float4 r = *(const float4*)(transfer + (lane + 64 * k) * L + gcb);
        E[k][0] = __expf(r.x); E[k][1] = __expf(r.y);
        E[k][2] = __expf(r.z); E[k][3] = __expf(r.w);
    }

    // ---------------- init: step-0 scores = feats[0], tag 0 ----------------
    if (tid < CPB) {
        int j = b * CPB + tid;
        __hip_atomic_store(&buf0[j], pack_su(0, feats[j]), __ATOMIC_RELAXED, SCOPE_AGENT);
    }

    // ---------------- sequential chain: ONE barrier per step ----------------
    for (int t = 1; t < T_LEN; ++t) {
        uint64_t* rbuf = (t & 1) ? buf0 : buf1;     // holds step t-1
        uint64_t* wbuf = (t & 1) ? buf1 : buf0;     // will hold step t
        const int expect = t - 1;

        // emission for my column (global load overlaps the poll)
        const float fe = feats[t * L + gcb + cl];

        // light poll (R2 pattern): 4 contiguous own slots (one publisher wave per
        // line) + broadcast slot 16b (same addr across block -> 1 req/wave).
        const uint64_t* rp = rbuf + 4 * tid;
        uint64_t v0, v1, v2, v3, vs;
        int n = 0;
        for (;;) {
            v0 = __hip_atomic_load(rp + 0, __ATOMIC_RELAXED, SCOPE_AGENT);
            v1 = __hip_atomic_load(rp + 1, __ATOMIC_RELAXED, SCOPE_AGENT);
            v2 = __hip_atomic_load(rp + 2, __ATOMIC_RELAXED, SCOPE_AGENT);
            v3 = __hip_atomic_load(rp + 3, __ATOMIC_RELAXED, SCOPE_AGENT);
            vs = __hip_atomic_load(rbuf + shslot, __ATOMIC_RELAXED, SCOPE_AGENT);
            bool ready = ((int)(v0 >> 32) >= expect) & ((int)(v1 >> 32) >= expect) &
                         ((int)(v2 >> 32) >= expect) & ((int)(v3 >> 32) >= expect) &
                         ((int)(vs >> 32) >= expect);
            if (ready || ++n >= SPIN_MAX) break;
        }
        const float sloc = __uint_as_float((uint32_t)vs);

        // q = exp(prev - sloc) -> LDS broadcast (double-buffered)
        float* qb = qbuf[t & 1];
        float4 qv;
        qv.x = __expf(__uint_as_float((uint32_t)v0) - sloc);
        qv.y = __expf(__uint_as_float((uint32_t)v1) - sloc);
        qv.z = __expf(__uint_as_float((uint32_t)v2) - sloc);
        qv.w = __expf(__uint_as_float((uint32_t)v3) - sloc);
        ((float4*)qb)[tid] = qv;
        __syncthreads();

        // matvec from registers: acc[c] += q[lane+64k] * E[k][c]
        float a0 = 0.f, a1 = 0.f, a2 = 0.f, a3 = 0.f;
        #pragma unroll
        for (int k = 0; k < 16; ++k) {
            const float q = qb[lane + 64 * k];       // conflict-free ds_read_b32
            a0 += q * E[k][0]; a1 += q * E[k][1];
            a2 += q * E[k][2]; a3 += q * E[k][3];
        }

        // split-reduction over 64 lanes: 4 accs -> 1 value per lane, col = cl
        {
            const bool hi1 = lane & 1;
            float s0 = hi1 ? a0 : a2;  float r0 = __shfl_xor(s0, 1, 64);
            float s1 = hi1 ? a1 : a3;  float r1 = __shfl_xor(s1, 1, 64);
            a0 = (hi1 ? a2 : a0) + r0;
            a1 = (hi1 ? a3 : a1) + r1;
            const bool hi2 = lane & 2;
            float s2 = hi2 ? a0 : a1;  float r2 = __shfl_xor(s2, 2, 64);
            a0 = (hi2 ? a1 : a0) + r2;
        }
        float s = a0;
        s += __shfl_xor(s, 4, 64);
        s += __shfl_xor(s, 8, 64);
        s += __shfl_xor(s, 16, 64);
        s += __shfl_xor(s, 32, 64);

        const float nv = sloc + __logf(s) + fe;     // new score for column gcb+cl
        if (lane < 4)
            __hip_atomic_store(&wbuf[gcb + cl], pack_su(t, nv), __ATOMIC_RELAXED, SCOPE_AGENT);
    }

    // ---------------- epilogue: block 0 computes logZ - gold ----------------
    if (b == 0) {
        const uint64_t* fp = buf1 + 4 * tid;        // t=2047 (odd) wrote buf1
        uint64_t v0, v1, v2, v3;
        int n = 0;
        for (;;) {
            v0 = __hip_atomic_load(fp + 0, __ATOMIC_RELAXED, SCOPE_AGENT);
            v1 = __hip_atomic_load(fp + 1, __ATOMIC_RELAXED, SCOPE_AGENT);
            v2 = __hip_atomic_load(fp + 2, __ATOMIC_RELAXED, SCOPE_AGENT);
            v3 = __hip_atomic_load(fp + 3, __ATOMIC_RELAXED, SCOPE_AGENT);
            bool ready = ((int)(v0 >> 32) >= T_LEN - 1) & ((int)(v1 >> 32) >= T_LEN - 1) &
                         ((int)(v2 >> 32) >= T_LEN - 1) & ((int)(v3 >> 32) >= T_LEN - 1);
            if (ready || ++n >= SPIN_MAX) break;
        }
        float sv[4] = { __uint_as_float((uint32_t)v0), __uint_as_float((uint32_t)v1),
                        __uint_as_float((uint32_t)v2), __uint_as_float((uint32_t)v3) };
        float mx = fmaxf(fmaxf(sv[0], sv[1]), fmaxf(sv[2], sv[3]));
        #pragma unroll
        for (int m = 32; m; m >>= 1) mx = fmaxf(mx, __shfl_xor(mx, m, 64));
        if ((tid & 63) == 0) red[tid >> 6] = mx;
        __syncthreads();
        const float M = fmaxf(fmaxf(red[0], red[1]), fmaxf(red[2], red[3]));
        float sm = 0.f;
        #pragma unroll
        for (int k = 0; k < 4; ++k) sm += __expf(sv[k] - M);
        #pragma unroll
        for (int m = 32; m; m >>= 1) sm += __shfl_xor(sm, m, 64);
        if ((tid & 63) == 0) red[4 + (tid >> 6)] = sm;
        __syncthreads();
        if (tid == 0) {
            const float S = red[4] + red[5] + red[6] + red[7];
            const float lse = M + __logf(S);
            uint64_t g = __hip_atomic_load(goldslot, __ATOMIC_RELAXED, SCOPE_AGENT);
            int n2 = 0;
            while ((int)(g >> 32) < 1 && ++n2 < SPIN_MAX)
                g = __hip_atomic_load(goldslot, __ATOMIC_RELAXED, SCOPE_AGENT);
            out[0] = lse - __uint_as_float((uint32_t)g);
        }
    }
}

extern "C" void kernel_launch(void* const* d_in, const int* in_sizes, int n_in,
                              void* d_out, int out_size, void* d_ws, size_t ws_size,
                              hipStream_t stream) {
    const float* feats    = (const float*)d_in[0];
    const float* transfer = (const float*)d_in[1];
    const int*   target   = (const int*)d_in[2];
    float* out = (float*)d_out;
    uint64_t* ws64 = (uint64_t*)d_ws;   // needs (2*L + 1) * 8 = 16392 bytes

    hipLaunchKernelGGL(crf_forward, dim3(KBLK + 1), dim3(TPB), 0, stream,
                       feats, transfer, target, out, ws64);
}